// Round 6
// baseline (206.435 us; speedup 1.0000x reference)
//
#include <hip/hip_runtime.h>
#include <hip/hip_bf16.h>

typedef __attribute__((ext_vector_type(4))) float  f32x4;
typedef __attribute__((ext_vector_type(8))) short  s16x8;
typedef __attribute__((ext_vector_type(4))) short  s16x4;

#define NB_    16
#define NH_    128
#define NS_    4096
#define ND_    512
#define NDPE_  64
#define NDT_   576
#define NCHUNK 16
#define CHUNK_ 256
#define TS_    32
#define NSUB_  8
#define NT_    1024          // 16 waves; wave pair = 16 heads (khalf 0: d 0..255, 1: d 256..511)

#define KROW_S 584           // kbuf row: 576 + 8 pad shorts
#define VT_ROW 34            // vbufT row: 32 + 2 pad shorts
#define PROW   40            // pbuf row: 32 + 8 pad shorts
#define SROW   20            // sbuf row: 16 + 4 pad f32

#define KBUF_BYTES (TS_ * KROW_S * 2)                  // 37376
#define VBUF_OFF   KBUF_BYTES
#define VBUF_BYTES (ND_ * VT_ROW * 2)                  // 34816
#define PBUF_OFF   (VBUF_OFF + VBUF_BYTES)             // 72192
#define PBUF_BYTES (16 * 16 * PROW * 2)                // 20480
#define SBUF_OFF   (PBUF_OFF + PBUF_BYTES)             // 92672
#define SBUF_BYTES (8 * 2 * TS_ * SROW * 4)            // 40960
#define SMEM_BYTES (SBUF_OFF + SBUF_BYTES)             // 133632 <= 163840

// (1/sqrt(576)) * log2(e)
#define CL2 0.06011229337037348f

__device__ __forceinline__ unsigned pk_bf16(float a, float b) {
    union { __hip_bfloat162 h2; unsigned u; } c;
    c.h2 = __float22bfloat162_rn(make_float2(a, b));
    return c.u;
}
__device__ __forceinline__ unsigned short bf1(float a) {
    union { __hip_bfloat16 h; unsigned short u; } c;
    c.h = __float2bfloat16(a);
    return c.u;
}

__global__ void qcvt(const float* __restrict__ q, const float* __restrict__ q_pe,
                     unsigned short* __restrict__ qbf) {
    const int idx = blockIdx.x * 256 + threadIdx.x;   // pair index
    if (idx >= NB_ * NH_ * (NDT_ / 2)) return;
    const int bh = idx / (NDT_ / 2), pc = idx - bh * (NDT_ / 2);
    const int c = pc * 2;
    const float* src = (c < ND_) ? (q + (size_t)bh * ND_ + c)
                                 : (q_pe + (size_t)bh * NDPE_ + (c - ND_));
    *(unsigned*)&qbf[(size_t)bh * NDT_ + c] = pk_bf16(src[0], src[1]);
}

__global__ __launch_bounds__(NT_, 1) void mla_attn(
    const float* __restrict__ k, const float* __restrict__ k_pe,
    const unsigned short* __restrict__ qbf,
    unsigned short* __restrict__ opart, float* __restrict__ mlbuf)
{
    extern __shared__ char smem[];
    unsigned short* kbuf = (unsigned short*)(smem);              // [32][584] bf16
    unsigned short* vbuf = (unsigned short*)(smem + VBUF_OFF);   // [512][34] bf16 (V^T)
    unsigned short* pbuf = (unsigned short*)(smem + PBUF_OFF);   // 16 waves x [16][40]
    float*          sbuf = (float*)(smem + SBUF_OFF);            // 8 grp x 2 half x [32][20]

    const int chunk = blockIdx.x, b = blockIdx.y;
    const int tid   = threadIdx.x;
    const int wv    = tid >> 6;
    const int grp   = wv >> 1;       // 0..7 : 16-head group
    const int khalf = wv & 1;        // 0/1  : QK k-half AND PV d-half
    const int l     = tid & 63;
    const int l16   = l & 15;
    const int lq    = l >> 4;

    f32x4 acc[16];
    #pragma unroll
    for (int i = 0; i < 16; ++i) acc[i] = (f32x4)0.0f;
    float m2[4]   = {-1e30f, -1e30f, -1e30f, -1e30f};
    float lsum[4] = {0.f, 0.f, 0.f, 0.f};

    const unsigned short* qrowb =
        qbf + (size_t)(b * NH_ + grp * 16 + l16) * NDT_ + khalf * 288 + lq * 8;

    unsigned short* prow = pbuf + wv * 16 * PROW;
    float* smy = sbuf + grp * (2 * TS_ * SROW) + khalf * (TS_ * SROW);
    const float* sot = sbuf + grp * (2 * TS_ * SROW) + (khalf ^ 1) * (TS_ * SROW);

    // staging decomposition (coalesced): lane-consecutive in d
    const int s_r  = tid >> 7;          // k: row group base (8 rows/pass, 4 passes)
    const int s_d  = (tid & 127) * 4;   // k: dword col 0..508
    const int p_r  = tid >> 4;          // pe: row 0..31 (tid<512)
    const int p_d  = (tid & 15) * 4;    // pe: dword col 0..60

    for (int t = 0; t < NSUB_; ++t) {
        // ---------------- stage tile: f32 -> bf16 kbuf + V^T scatter ----------------
        {
            const int sbase = b * NS_ + chunk * CHUNK_ + t * TS_;
            #pragma unroll
            for (int j = 0; j < 4; ++j) {
                const int r = s_r + 8 * j;
                const f32x4 v = *(const f32x4*)(k + (size_t)(sbase + r) * ND_ + s_d);
                const unsigned lo = pk_bf16(v.x, v.y), hi = pk_bf16(v.z, v.w);
                *(unsigned long long*)&kbuf[r * KROW_S + s_d] =
                    (unsigned long long)lo | ((unsigned long long)hi << 32);
                vbuf[(s_d + 0) * VT_ROW + r] = (unsigned short)(lo);
                vbuf[(s_d + 1) * VT_ROW + r] = (unsigned short)(lo >> 16);
                vbuf[(s_d + 2) * VT_ROW + r] = (unsigned short)(hi);
                vbuf[(s_d + 3) * VT_ROW + r] = (unsigned short)(hi >> 16);
            }
            if (tid < 512) {
                const f32x4 v = *(const f32x4*)(k_pe + (size_t)(sbase + p_r) * NDPE_ + p_d);
                const unsigned lo = pk_bf16(v.x, v.y), hi = pk_bf16(v.z, v.w);
                *(unsigned long long*)&kbuf[p_r * KROW_S + ND_ + p_d] =
                    (unsigned long long)lo | ((unsigned long long)hi << 32);
            }
        }
        __syncthreads();

        // ---------------- QK^T (own 288-dim k-half): 9 x 2 MFMA ----------------
        // opaque pointer: stop the compiler from hoisting 36 regs of Q out of the t-loop
        const unsigned short* qp = qrowb;
        asm volatile("" : "+v"(qp));
        f32x4 sc0 = (f32x4)0.0f, sc1 = (f32x4)0.0f;
        #pragma unroll
        for (int i = 0; i < 9; ++i) {
            const int d0 = khalf * 288 + i * 32 + lq * 8;
            const s16x8 af = *(const s16x8*)(qp + i * 32);
            const s16x8 b0 = *(const s16x8*)&kbuf[(l16     ) * KROW_S + d0];
            const s16x8 b1 = *(const s16x8*)&kbuf[(l16 + 16) * KROW_S + d0];
            sc0 = __builtin_amdgcn_mfma_f32_16x16x32_bf16(af, b0, sc0, 0, 0, 0);
            sc1 = __builtin_amdgcn_mfma_f32_16x16x32_bf16(af, b1, sc1, 0, 0, 0);
        }

        // ---------------- exchange partial scores with partner wave ----------------
        *(f32x4*)&smy[(l16     ) * SROW + lq * 4] = sc0;
        *(f32x4*)&smy[(l16 + 16) * SROW + lq * 4] = sc1;
        __syncthreads();
        sc0 += *(const f32x4*)&sot[(l16     ) * SROW + lq * 4];
        sc1 += *(const f32x4*)&sot[(l16 + 16) * SROW + lq * 4];

        // ---------------- online softmax (base-2, scale folded) ----------------
        float alpha[4];
        #pragma unroll
        for (int r = 0; r < 4; ++r) {
            float mx = fmaxf(sc0[r], sc1[r]);
            mx = fmaxf(mx, __shfl_xor(mx, 1));
            mx = fmaxf(mx, __shfl_xor(mx, 2));
            mx = fmaxf(mx, __shfl_xor(mx, 4));
            mx = fmaxf(mx, __shfl_xor(mx, 8));
            const float mn = fmaxf(m2[r], mx * CL2);
            const float al = exp2f(m2[r] - mn);
            const float p0 = exp2f(fmaf(sc0[r], CL2, -mn));
            const float p1 = exp2f(fmaf(sc1[r], CL2, -mn));
            float sm = p0 + p1;
            sm += __shfl_xor(sm, 1);
            sm += __shfl_xor(sm, 2);
            sm += __shfl_xor(sm, 4);
            sm += __shfl_xor(sm, 8);
            lsum[r] = al * lsum[r] + sm;
            m2[r] = mn;
            alpha[r] = al;
            prow[(lq * 4 + r) * PROW + l16]      = bf1(p0);
            prow[(lq * 4 + r) * PROW + 16 + l16] = bf1(p1);
        }
        #pragma unroll
        for (int nf = 0; nf < 16; ++nf) {
            acc[nf][0] *= alpha[0];
            acc[nf][1] *= alpha[1];
            acc[nf][2] *= alpha[2];
            acc[nf][3] *= alpha[3];
        }
        // P writes are wave-locally consumed: drain LDS, pin order
        asm volatile("s_waitcnt lgkmcnt(0)" ::: "memory");
        __builtin_amdgcn_sched_barrier(0);

        // ---------------- PV (own d-half): acc[16h x 256d] += P[16x32] V[32x256] ----------------
        const s16x8 pf = *(const s16x8*)&prow[l16 * PROW + lq * 8];
        const int doff = khalf * 256;
        #pragma unroll
        for (int nf = 0; nf < 16; ++nf) {
            const int ro = (doff + nf * 16 + l16) * VT_ROW + lq * 8;
            union { s16x4 h[2]; s16x8 v; } u;
            u.h[0] = *(const s16x4*)&vbuf[ro];
            u.h[1] = *(const s16x4*)&vbuf[ro + 4];
            acc[nf] = __builtin_amdgcn_mfma_f32_16x16x32_bf16(pf, u.v, acc[nf], 0, 0, 0);
        }
        __syncthreads();   // all LDS reads done before next tile's staging writes
    }

    // ---------------- write partials (unnormalized O bf16, + m,l) ----------------
    const size_t obase = (size_t)(b * NCHUNK + chunk) * NH_ * ND_;
    const int doff = khalf * 256;
    #pragma unroll
    for (int nf = 0; nf < 16; ++nf) {
        #pragma unroll
        for (int r = 0; r < 4; ++r) {
            const int h = grp * 16 + lq * 4 + r;
            const int d = doff + nf * 16 + l16;
            opart[obase + (size_t)h * ND_ + d] = bf1(acc[nf][r]);
        }
    }
    if (khalf == 0 && l16 == 0) {
        #pragma unroll
        for (int r = 0; r < 4; ++r) {
            const int h = grp * 16 + lq * 4 + r;
            const int idx = (b * NCHUNK + chunk) * NH_ + h;
            mlbuf[2 * idx]     = m2[r];
            mlbuf[2 * idx + 1] = lsum[r];
        }
    }
}

__global__ __launch_bounds__(128) void mla_combine(
    const unsigned short* __restrict__ opart, const float* __restrict__ mlbuf,
    float* __restrict__ out)
{
    const int bh = blockIdx.x;
    const int b = bh >> 7, h = bh & 127;
    const int tid = threadIdx.x;

    float mv[NCHUNK], lv[NCHUNK];
    float m = -1e30f;
    #pragma unroll
    for (int c = 0; c < NCHUNK; ++c) {
        const int idx = (b * NCHUNK + c) * NH_ + h;
        mv[c] = mlbuf[2 * idx];
        lv[c] = mlbuf[2 * idx + 1];
        m = fmaxf(m, mv[c]);
    }
    float L = 0.f, w[NCHUNK];
    #pragma unroll
    for (int c = 0; c < NCHUNK; ++c) { w[c] = exp2f(mv[c] - m); L += w[c] * lv[c]; }
    const float inv = 1.0f / L;

    const int d0 = tid * 4;
    float a0 = 0.f, a1 = 0.f, a2 = 0.f, a3 = 0.f;
    #pragma unroll
    for (int c = 0; c < NCHUNK; ++c) {
        const unsigned short* p = opart + (((size_t)(b * NCHUNK + c) * NH_ + h) * ND_ + d0);
        const unsigned u0 = *(const unsigned*)(p);
        const unsigned u1 = *(const unsigned*)(p + 2);
        a0 += w[c] * __uint_as_float((u0 & 0xffffu) << 16);
        a1 += w[c] * __uint_as_float(u0 & 0xffff0000u);
        a2 += w[c] * __uint_as_float((u1 & 0xffffu) << 16);
        a3 += w[c] * __uint_as_float(u1 & 0xffff0000u);
    }
    f32x4 res;
    res.x = a0 * inv; res.y = a1 * inv; res.z = a2 * inv; res.w = a3 * inv;
    *(f32x4*)(out + ((size_t)(b * NH_ + h) * ND_ + d0)) = res;
}

extern "C" void kernel_launch(void* const* d_in, const int* in_sizes, int n_in,
                              void* d_out, int out_size, void* d_ws, size_t ws_size,
                              hipStream_t stream) {
    const float* q    = (const float*)d_in[0];
    const float* q_pe = (const float*)d_in[1];
    const float* k    = (const float*)d_in[2];
    const float* k_pe = (const float*)d_in[3];

    unsigned short* opart = (unsigned short*)d_ws;
    float* mlbuf = (float*)((char*)d_ws + (size_t)NB_ * NCHUNK * NH_ * ND_ * sizeof(unsigned short));
    unsigned short* qbf = (unsigned short*)((char*)mlbuf + (size_t)NB_ * NCHUNK * NH_ * 2 * sizeof(float));

    const int qpairs = NB_ * NH_ * (NDT_ / 2);
    qcvt<<<(qpairs + 255) / 256, 256, 0, stream>>>(q, q_pe, qbf);
    mla_attn<<<dim3(NCHUNK, NB_), NT_, SMEM_BYTES, stream>>>(k, k_pe, qbf, opart, mlbuf);
    mla_combine<<<NB_ * NH_, 128, 0, stream>>>(opart, mlbuf, (float*)d_out);
}